// Round 4
// baseline (435.323 us; speedup 1.0000x reference)
//
#include <hip/hip_runtime.h>
#include <hip/hip_bf16.h>

typedef unsigned short u16;
typedef unsigned int   u32;

static constexpr int Bc = 8, Ac = 64, Tc = 128, Cc = 256, Hc = 8;
static constexpr int NROW = Bc * Ac * Tc;   // 65536 tokens
static constexpr int DH = Cc / Hc;          // 32

__device__ __forceinline__ float bf2f(u16 h) {
    u32 u = ((u32)h) << 16; float f; __builtin_memcpy(&f, &u, 4); return f;
}
__device__ __forceinline__ u16 f2bf(float f) {
    u32 u; __builtin_memcpy(&u, &f, 4);
    u += 0x7fffu + ((u >> 16) & 1u);   // RNE
    return (u16)(u >> 16);
}

typedef __attribute__((ext_vector_type(8))) short  short8v;
typedef __attribute__((ext_vector_type(4))) float  float4v;

__device__ __forceinline__ void gload16(const void* g, const void* lds) {
    __builtin_amdgcn_global_load_lds(
        (const __attribute__((address_space(1))) void*)g,
        (__attribute__((address_space(3))) void*)lds, 16, 0, 0);
}

// ---------------- cast all weights fp32 -> bf16, one launch ----------------
__global__ void cast4_kernel(const float* __restrict__ a, int na,
                             const float* __restrict__ b, int nb,
                             const float* __restrict__ c, int nc,
                             const float* __restrict__ d, int nd,
                             u16* oa, u16* ob, u16* oc, u16* od) {
    int i = blockIdx.x * 256 + threadIdx.x;
    if (i < na) { oa[i] = f2bf(a[i]); return; }
    i -= na;
    if (i < nb) { ob[i] = f2bf(b[i]); return; }
    i -= nb;
    if (i < nc) { oc[i] = f2bf(c[i]); return; }
    i -= nc;
    if (i < nd) { od[i] = f2bf(d[i]); }
}

// ---------------- LayerNorm, fp32 input -> bf16 out ----------------
__global__ __launch_bounds__(256) void ln_f32(const float* __restrict__ in,
        const float* __restrict__ w, const float* __restrict__ b,
        u16* __restrict__ out) {
    int row  = blockIdx.x * 4 + (threadIdx.x >> 6);
    int lane = threadIdx.x & 63;
    const float* rp = in + (size_t)row * Cc + lane * 4;
    float4 v = *(const float4*)rp;
    float s  = v.x + v.y + v.z + v.w;
    float sq = v.x * v.x + v.y * v.y + v.z * v.z + v.w * v.w;
    for (int off = 32; off; off >>= 1) { s += __shfl_xor(s, off); sq += __shfl_xor(sq, off); }
    float mean = s * (1.f / Cc);
    float rs = rsqrtf(sq * (1.f / Cc) - mean * mean + 1e-5f);
    int c0 = lane * 4;
    float vv[4] = {v.x, v.y, v.z, v.w};
    ushort4 ov;
    ov.x = f2bf((vv[0] - mean) * rs * w[c0 + 0] + b[c0 + 0]);
    ov.y = f2bf((vv[1] - mean) * rs * w[c0 + 1] + b[c0 + 1]);
    ov.z = f2bf((vv[2] - mean) * rs * w[c0 + 2] + b[c0 + 2]);
    ov.w = f2bf((vv[3] - mean) * rs * w[c0 + 3] + b[c0 + 3]);
    *(ushort4*)(out + (size_t)row * Cc + c0) = ov;
}

// ---- A-resident GEMM: out[128-rows/block][Nf] = X[.][256] @ W[Nf][256]^T ----
// NJ = Nf/64 chunks; EPI: 0 bias->bf16 | 1 bias+res->bf16
template<int NJ, int EPI>
__global__ __launch_bounds__(512) void gemm_ares(
        const u16* __restrict__ X, const u16* __restrict__ W,
        const float* __restrict__ bias,
        u16* __restrict__ outb, const u16* __restrict__ res, int Nf) {
    __shared__ __align__(16) u16 lA[32][128][8];      // 64 KB: full A tile, frag order
    __shared__ __align__(16) u16 lW[2][32][64][8];    // 2 x 32 KB: weight chunk dbuf
    const int bm   = blockIdx.x * 128;
    const int tid  = threadIdx.x, lane = tid & 63, wave = tid >> 6;
    const int lr   = lane & 15,  lg   = lane >> 4;
    const int wr   = (wave >> 1) * 32;   // 4 M-groups of 32 rows
    const int wc   = (wave & 1) * 32;    // 2 N-groups of 32 cols

    // prologue: stage A (4096 chunks) + first weight chunk (2048 chunks)
    #pragma unroll
    for (int r = 0; r < 8; r++) {
        const int cb = r * 512 + wave * 64;           // wave-uniform
        const int d  = cb + lane;
        const int kc = d >> 7, row = d & 127;
        gload16(X + (size_t)(bm + row) * 256 + kc * 8, (const u16*)lA + (size_t)cb * 8);
    }
    #pragma unroll
    for (int r = 0; r < 4; r++) {
        const int cb = r * 512 + wave * 64;
        const int d  = cb + lane;
        const int kc = d >> 6, row = d & 63;
        gload16(W + (size_t)row * 256 + kc * 8, (const u16*)&lW[0][0][0][0] + (size_t)cb * 8);
    }
    __syncthreads();

    // hoist A fragments: 16 ds_read_b128, reused across all chunks
    short8v a_all[8][2];
    #pragma unroll
    for (int s = 0; s < 8; s++) {
        a_all[s][0] = *(const short8v*)&lA[s * 4 + lg][wr + lr][0];
        a_all[s][1] = *(const short8v*)&lA[s * 4 + lg][wr + 16 + lr][0];
    }

    for (int j = 0; j < NJ; j++) {
        if (j + 1 < NJ) {   // prefetch next weight chunk into other buffer
            #pragma unroll
            for (int r = 0; r < 4; r++) {
                const int cb = r * 512 + wave * 64;
                const int d  = cb + lane;
                const int kc = d >> 6, row = d & 63;
                gload16(W + (size_t)((j + 1) * 64 + row) * 256 + kc * 8,
                        (const u16*)&lW[(j + 1) & 1][0][0][0] + (size_t)cb * 8);
            }
        }
        const u16 (*lWc)[64][8] = lW[j & 1];
        float4v acc[2][2] = {};
        #pragma unroll
        for (int s = 0; s < 8; s++) {
            short8v b0 = *(const short8v*)&lWc[s * 4 + lg][wc + lr][0];
            short8v b1 = *(const short8v*)&lWc[s * 4 + lg][wc + 16 + lr][0];
            acc[0][0] = __builtin_amdgcn_mfma_f32_16x16x32_bf16(a_all[s][0], b0, acc[0][0], 0, 0, 0);
            acc[0][1] = __builtin_amdgcn_mfma_f32_16x16x32_bf16(a_all[s][0], b1, acc[0][1], 0, 0, 0);
            acc[1][0] = __builtin_amdgcn_mfma_f32_16x16x32_bf16(a_all[s][1], b0, acc[1][0], 0, 0, 0);
            acc[1][1] = __builtin_amdgcn_mfma_f32_16x16x32_bf16(a_all[s][1], b1, acc[1][1], 0, 0, 0);
        }
        // epilogue for this 128x64 chunk
        #pragma unroll
        for (int jj = 0; jj < 2; jj++) {
            const int c = j * 64 + wc + jj * 16 + lr;
            const float bv = bias[c];
            #pragma unroll
            for (int i = 0; i < 2; i++)
                #pragma unroll
                for (int rq = 0; rq < 4; rq++) {
                    const int row = bm + wr + i * 16 + lg * 4 + rq;
                    float v = acc[i][jj][rq] + bv;
                    const size_t oidx = (size_t)row * Nf + c;
                    if (EPI == 1) v += bf2f(res[oidx]);
                    outb[oidx] = f2bf(v);
                }
        }
        __syncthreads();   // drains prefetch vmcnt; guards buffer swap
    }
}

// ---- fused MLP: LN2 + fc1 + GELU + fc2 + residual, per 128-row block ----
__global__ __launch_bounds__(512) void mlp_fused(
        const u16* __restrict__ x2,
        const float* __restrict__ ln2w, const float* __restrict__ ln2b,
        const u16* __restrict__ w1, const float* __restrict__ b1,
        const u16* __restrict__ w2, const float* __restrict__ b2,
        float* __restrict__ out) {
    __shared__ __align__(16) u16 lX[32][128][8];   // x3 tile, 64 KB
    __shared__ __align__(16) u16 lW1[32][64][8];   // 32 KB
    __shared__ __align__(16) u16 lW2[8][256][8];   // 32 KB
    __shared__ __align__(16) u16 lH[8][128][8];    // 16 KB
    const int bm   = blockIdx.x * 128;
    const int tid  = threadIdx.x, lane = tid & 63, wave = tid >> 6;
    const int lr   = lane & 15,  lg   = lane >> 4;
    const int wr   = (wave >> 1) * 32;   // M rows (fc1 & fc2)
    const int wc1  = (wave & 1) * 32;    // fc1 N (h cols in chunk)
    const int wc2  = (wave & 1) * 128;   // fc2 N (out cols)

    // ---- LN2: x3 = LN(x2) -> lX (frag order); 4 threads per row ----
    {
        const int row = tid >> 2, q = tid & 3;
        const u16* rp = x2 + (size_t)(bm + row) * 256 + q * 64;
        uint4 rv[8];
        #pragma unroll
        for (int g = 0; g < 8; g++) rv[g] = ((const uint4*)rp)[g];
        float s = 0.f, sq = 0.f;
        #pragma unroll
        for (int g = 0; g < 8; g++) {
            const u16* e = (const u16*)&rv[g];
            #pragma unroll
            for (int t = 0; t < 8; t++) { float f = bf2f(e[t]); s += f; sq += f * f; }
        }
        s  += __shfl_xor(s, 1);  s  += __shfl_xor(s, 2);
        sq += __shfl_xor(sq, 1); sq += __shfl_xor(sq, 2);
        const float mean = s * (1.f / 256.f);
        const float rs = rsqrtf(sq * (1.f / 256.f) - mean * mean + 1e-5f);
        #pragma unroll
        for (int g = 0; g < 8; g++) {
            const int c0 = q * 64 + g * 8;
            float4 w4a = *(const float4*)(ln2w + c0), w4b = *(const float4*)(ln2w + c0 + 4);
            float4 b4a = *(const float4*)(ln2b + c0), b4b = *(const float4*)(ln2b + c0 + 4);
            const u16* e = (const u16*)&rv[g];
            u16 o[8];
            o[0] = f2bf((bf2f(e[0]) - mean) * rs * w4a.x + b4a.x);
            o[1] = f2bf((bf2f(e[1]) - mean) * rs * w4a.y + b4a.y);
            o[2] = f2bf((bf2f(e[2]) - mean) * rs * w4a.z + b4a.z);
            o[3] = f2bf((bf2f(e[3]) - mean) * rs * w4a.w + b4a.w);
            o[4] = f2bf((bf2f(e[4]) - mean) * rs * w4b.x + b4b.x);
            o[5] = f2bf((bf2f(e[5]) - mean) * rs * w4b.y + b4b.y);
            o[6] = f2bf((bf2f(e[6]) - mean) * rs * w4b.z + b4b.z);
            o[7] = f2bf((bf2f(e[7]) - mean) * rs * w4b.w + b4b.w);
            *(uint4*)&lX[c0 >> 3][row][0] = *(uint4*)o;
        }
    }
    // ---- stage j=0 weights ----
    #pragma unroll
    for (int r = 0; r < 4; r++) {
        const int cb = r * 512 + wave * 64;
        const int d  = cb + lane;
        const int kc = d >> 6, row = d & 63;
        gload16(w1 + (size_t)row * 256 + kc * 8, (const u16*)&lW1[0][0][0] + (size_t)cb * 8);
    }
    #pragma unroll
    for (int r = 0; r < 4; r++) {
        const int cb = r * 512 + wave * 64;
        const int d  = cb + lane;
        const int kc = d >> 8, n = d & 255;
        gload16(w2 + (size_t)n * 1024 + kc * 8, (const u16*)&lW2[0][0][0] + (size_t)cb * 8);
    }
    __syncthreads();

    float4v acc_o[2][8] = {};
    for (int j = 0; j < 16; j++) {
        // prefetch next chunk's weights into registers (T14)
        uint4 pf[8];
        if (j < 15) {
            #pragma unroll
            for (int r = 0; r < 4; r++) {
                const int d = r * 512 + tid;
                const int kc = d >> 6, row = d & 63;
                pf[r] = *(const uint4*)(w1 + (size_t)((j + 1) * 64 + row) * 256 + kc * 8);
            }
            #pragma unroll
            for (int r = 0; r < 4; r++) {
                const int d = r * 512 + tid;
                const int kc = d >> 8, n = d & 255;
                pf[4 + r] = *(const uint4*)(w2 + (size_t)n * 1024 + (j + 1) * 64 + kc * 8);
            }
        }
        // ---- fc1: hj[128][64] = gelu(x3 @ w1_j^T + b1_j) ----
        float4v ah[2][2] = {};
        #pragma unroll
        for (int s = 0; s < 8; s++) {
            short8v a0 = *(const short8v*)&lX[s * 4 + lg][wr + lr][0];
            short8v a1 = *(const short8v*)&lX[s * 4 + lg][wr + 16 + lr][0];
            short8v b0 = *(const short8v*)&lW1[s * 4 + lg][wc1 + lr][0];
            short8v b1v = *(const short8v*)&lW1[s * 4 + lg][wc1 + 16 + lr][0];
            ah[0][0] = __builtin_amdgcn_mfma_f32_16x16x32_bf16(a0, b0, ah[0][0], 0, 0, 0);
            ah[0][1] = __builtin_amdgcn_mfma_f32_16x16x32_bf16(a0, b1v, ah[0][1], 0, 0, 0);
            ah[1][0] = __builtin_amdgcn_mfma_f32_16x16x32_bf16(a1, b0, ah[1][0], 0, 0, 0);
            ah[1][1] = __builtin_amdgcn_mfma_f32_16x16x32_bf16(a1, b1v, ah[1][1], 0, 0, 0);
        }
        #pragma unroll
        for (int jj = 0; jj < 2; jj++) {
            const int c = wc1 + jj * 16 + lr;
            const float bv = b1[j * 64 + c];
            #pragma unroll
            for (int i = 0; i < 2; i++)
                #pragma unroll
                for (int rq = 0; rq < 4; rq++) {
                    const int row = wr + i * 16 + lg * 4 + rq;
                    float v = ah[i][jj][rq] + bv;
                    v = 0.5f * v * (1.f + erff(v * 0.70710678118654752f));
                    lH[c >> 3][row][c & 7] = f2bf(v);
                }
        }
        __syncthreads();   // lH ready; all lW1 reads done

        // ---- fc2 accumulate: out += hj @ w2_j^T ----
        #pragma unroll
        for (int s2 = 0; s2 < 2; s2++) {
            short8v ahf0 = *(const short8v*)&lH[s2 * 4 + lg][wr + lr][0];
            short8v ahf1 = *(const short8v*)&lH[s2 * 4 + lg][wr + 16 + lr][0];
            #pragma unroll
            for (int j2 = 0; j2 < 8; j2++) {
                short8v bw = *(const short8v*)&lW2[s2 * 4 + lg][wc2 + j2 * 16 + lr][0];
                acc_o[0][j2] = __builtin_amdgcn_mfma_f32_16x16x32_bf16(ahf0, bw, acc_o[0][j2], 0, 0, 0);
                acc_o[1][j2] = __builtin_amdgcn_mfma_f32_16x16x32_bf16(ahf1, bw, acc_o[1][j2], 0, 0, 0);
            }
        }
        __syncthreads();   // all lH / lW2 reads done

        if (j < 15) {      // commit prefetched weights to LDS
            #pragma unroll
            for (int r = 0; r < 4; r++) {
                const int d = r * 512 + tid;
                *(uint4*)((u16*)&lW1[0][0][0] + (size_t)d * 8) = pf[r];
            }
            #pragma unroll
            for (int r = 0; r < 4; r++) {
                const int d = r * 512 + tid;
                *(uint4*)((u16*)&lW2[0][0][0] + (size_t)d * 8) = pf[4 + r];
            }
            __syncthreads();   // weights ready for next j
        }
    }

    // ---- epilogue: out = x3 + fc2 + b2 (fp32) ----
    float bb[8];
    #pragma unroll
    for (int j2 = 0; j2 < 8; j2++) bb[j2] = b2[wc2 + j2 * 16 + lr];
    #pragma unroll
    for (int i = 0; i < 2; i++)
        #pragma unroll
        for (int j2 = 0; j2 < 8; j2++)
            #pragma unroll
            for (int rq = 0; rq < 4; rq++) {
                const int row = wr + i * 16 + lg * 4 + rq;
                const int c2 = wc2 + j2 * 16 + lr;
                const float xv = bf2f(lX[c2 >> 3][row][c2 & 7]);
                out[(size_t)(bm + row) * 256 + c2] = acc_o[i][j2][rq] + bb[j2] + xv;
            }
}

// ---------------- MFMA attention: one block per (b,a), 4 waves, 8 heads ----------------
__global__ __launch_bounds__(256) void attn_mfma(
        const u16* __restrict__ qkv, const unsigned char* __restrict__ mask,
        u16* __restrict__ out) {
    __shared__ u16 sk[128][32];
    __shared__ u16 svt[32][136];
    __shared__ u16 sp[4][32][136];
    __shared__ unsigned char smask[128];
    const int ba = blockIdx.x;
    const size_t rowbase = (size_t)ba * Tc;
    const int tid  = threadIdx.x;
    const int lane = tid & 63;
    const int wave = tid >> 6;
    const int wq0  = wave * 32;
    const int lrow = lane & 15, lg = lane >> 4;
    if (tid < 128) smask[tid] = mask[rowbase + tid];

    const float scale  = 0.17677669529663687f;
    const float inv128 = 1.0f / 128.0f;

    for (int h = 0; h < Hc; h++) {
        {
            const int r = tid >> 1, half = tid & 1;
            const u16* gbase = qkv + (rowbase + r) * 768 + h * 32 + half * 16;
            uint4 k0 = *(const uint4*)(gbase + 256);
            uint4 k1 = *(const uint4*)(gbase + 256 + 8);
            *(uint4*)&sk[r][half * 16]     = k0;
            *(uint4*)&sk[r][half * 16 + 8] = k1;
            uint4 v0 = *(const uint4*)(gbase + 512);
            uint4 v1 = *(const uint4*)(gbase + 512 + 8);
            u16 vt[16];
            *(uint4*)&vt[0] = v0; *(uint4*)&vt[8] = v1;
            #pragma unroll
            for (int e = 0; e < 16; e++) svt[half * 16 + e][r] = vt[e];
        }
        __syncthreads();

        short8v a0, a1;
        {
            const u16* qp0 = qkv + (rowbase + wq0 + lrow) * 768 + h * 32 + lg * 8;
            const u16* qp1 = qp0 + 16 * 768;
            a0 = *(const short8v*)qp0;
            a1 = *(const short8v*)qp1;
        }
        float4v s_acc[2][8];
        #pragma unroll
        for (int j = 0; j < 8; j++) {
            short8v bj = *(const short8v*)&sk[j * 16 + lrow][lg * 8];
            s_acc[0][j] = __builtin_amdgcn_mfma_f32_16x16x32_bf16(a0, bj, (float4v){0.f,0.f,0.f,0.f}, 0, 0, 0);
            s_acc[1][j] = __builtin_amdgcn_mfma_f32_16x16x32_bf16(a1, bj, (float4v){0.f,0.f,0.f,0.f}, 0, 0, 0);
        }

        #pragma unroll
        for (int i = 0; i < 2; i++) {
            #pragma unroll
            for (int r = 0; r < 4; r++) {
                float m = s_acc[i][0][r];
                #pragma unroll
                for (int j = 1; j < 8; j++) m = fmaxf(m, s_acc[i][j][r]);
                #pragma unroll
                for (int off = 1; off < 16; off <<= 1) m = fmaxf(m, __shfl_xor(m, off));
                float sum = 0.f;
                #pragma unroll
                for (int j = 0; j < 8; j++) {
                    float e = __expf((s_acc[i][j][r] - m) * scale);
                    sum += e;
                    s_acc[i][j][r] = e;
                }
                #pragma unroll
                for (int off = 1; off < 16; off <<= 1) sum += __shfl_xor(sum, off);
                const int qloc = i * 16 + lg * 4 + r;
                const bool mk = smask[wq0 + qloc] != 0;
                const float invs = 1.f / sum;
                #pragma unroll
                for (int j = 0; j < 8; j++) {
                    float pv = mk ? inv128 : s_acc[i][j][r] * invs;
                    sp[wave][qloc][j * 16 + lrow] = f2bf(pv);
                }
            }
        }

        float4v o_acc[2][2] = {};
        #pragma unroll
        for (int t = 0; t < 4; t++) {
            short8v pa0 = *(const short8v*)&sp[wave][lrow][t * 32 + lg * 8];
            short8v pa1 = *(const short8v*)&sp[wave][16 + lrow][t * 32 + lg * 8];
            short8v vb0 = *(const short8v*)&svt[lrow][t * 32 + lg * 8];
            short8v vb1 = *(const short8v*)&svt[16 + lrow][t * 32 + lg * 8];
            o_acc[0][0] = __builtin_amdgcn_mfma_f32_16x16x32_bf16(pa0, vb0, o_acc[0][0], 0, 0, 0);
            o_acc[0][1] = __builtin_amdgcn_mfma_f32_16x16x32_bf16(pa0, vb1, o_acc[0][1], 0, 0, 0);
            o_acc[1][0] = __builtin_amdgcn_mfma_f32_16x16x32_bf16(pa1, vb0, o_acc[1][0], 0, 0, 0);
            o_acc[1][1] = __builtin_amdgcn_mfma_f32_16x16x32_bf16(pa1, vb1, o_acc[1][1], 0, 0, 0);
        }

        #pragma unroll
        for (int i = 0; i < 2; i++)
            #pragma unroll
            for (int n = 0; n < 2; n++)
                #pragma unroll
                for (int r = 0; r < 4; r++) {
                    size_t row = rowbase + wq0 + i * 16 + lg * 4 + r;
                    int col = h * 32 + n * 16 + lrow;
                    out[row * 256 + col] = f2bf(o_acc[i][n][r]);
                }
        __syncthreads();
    }
}

extern "C" void kernel_launch(void* const* d_in, const int* in_sizes, int n_in,
                              void* d_out, int out_size, void* d_ws, size_t ws_size,
                              hipStream_t stream) {
    const float* x      = (const float*)d_in[0];
    const unsigned char* mask = (const unsigned char*)d_in[1];
    const float* ln1_w  = (const float*)d_in[2];
    const float* ln1_b  = (const float*)d_in[3];
    const float* qkv_w  = (const float*)d_in[4];
    const float* qkv_b  = (const float*)d_in[5];
    const float* proj_w = (const float*)d_in[6];
    const float* proj_b = (const float*)d_in[7];
    const float* ln2_w  = (const float*)d_in[8];
    const float* ln2_b  = (const float*)d_in[9];
    const float* fc1_w  = (const float*)d_in[10];
    const float* fc1_b  = (const float*)d_in[11];
    const float* fc2_w  = (const float*)d_in[12];
    const float* fc2_b  = (const float*)d_in[13];
    float* out = (float*)d_out;

    char* ws = (char*)d_ws;
    size_t off = 0;
    auto alloc = [&](size_t elems) -> u16* {
        u16* p = (u16*)(ws + off);
        off += ((elems * 2 + 255) / 256) * 256;
        return p;
    };
    u16* wqb  = alloc(768 * 256);
    u16* wpb  = alloc(256 * 256);
    u16* w1b  = alloc(1024 * 256);
    u16* w2b  = alloc(256 * 1024);
    u16* x1b  = alloc((size_t)NROW * Cc);
    u16* qkvb = alloc((size_t)NROW * 3 * Cc);
    u16* attb = alloc((size_t)NROW * Cc);
    u16* x2b  = alloc((size_t)NROW * Cc);

    cast4_kernel<<<(786432 + 255) / 256, 256, 0, stream>>>(
        qkv_w, 196608, proj_w, 65536, fc1_w, 262144, fc2_w, 262144,
        wqb, wpb, w1b, w2b);
    ln_f32<<<NROW / 4, 256, 0, stream>>>(x, ln1_w, ln1_b, x1b);
    gemm_ares<12, 0><<<NROW / 128, 512, 0, stream>>>(
        x1b, wqb, qkv_b, qkvb, nullptr, 768);
    attn_mfma<<<Bc * Ac, 256, 0, stream>>>(qkvb, mask, attb);
    gemm_ares<4, 1><<<NROW / 128, 512, 0, stream>>>(
        attb, wpb, proj_b, x2b, x1b, 256);
    mlp_fused<<<NROW / 128, 512, 0, stream>>>(
        x2b, ln2_w, ln2_b, w1b, fc1_b, w2b, fc2_b, out);
}